// Round 1
// baseline (4028.216 us; speedup 1.0000x reference)
//
#include <hip/hip_runtime.h>

#define KNN 16
static constexpr int BB = 16;
static constexpr float LEAK = 0.2f;
static constexpr float EPSV = 1e-5f;

// ---------------- f0 = w_in @ coor + b_in  (point-major) ----------------
__global__ __launch_bounds__(256) void f0_kernel(const float* __restrict__ x,
    const float* __restrict__ w_in, const float* __restrict__ b_in,
    float* __restrict__ f0) {
  int i = blockIdx.x * 256 + threadIdx.x;
  if (i >= BB * 2048) return;
  float px = x[i*3+0], py = x[i*3+1], pz = x[i*3+2];
#pragma unroll
  for (int o = 0; o < 8; ++o) {
    f0[i*8+o] = w_in[o*3+0]*px + w_in[o*3+1]*py + w_in[o*3+2]*pz + b_in[o];
  }
}

// ---------------- kNN: per-thread top-16 insertion over LDS-staged keys ----
__global__ __launch_bounds__(256) void knn_kernel(const float* __restrict__ qxyz, int Nq,
    const float* __restrict__ kxyz, int Nk, int* __restrict__ idx) {
  __shared__ float4 keys[2048];
  int nqb = (Nq + 255) >> 8;
  int b = blockIdx.x / nqb;
  int q0 = (blockIdx.x % nqb) << 8;
  for (int j = threadIdx.x; j < Nk; j += 256) {
    const float* kp = kxyz + (size_t)(b*Nk + j)*3;
    float kx = kp[0], ky = kp[1], kz = kp[2];
    keys[j] = make_float4(kx, ky, kz, kx*kx + ky*ky + kz*kz);
  }
  __syncthreads();
  int q = q0 + threadIdx.x;
  if (q >= Nq) return;
  const float* qp = qxyz + (size_t)(b*Nq + q)*3;
  float qx = qp[0], qy = qp[1], qz = qp[2];
  float q2 = qx*qx + qy*qy + qz*qz;
  float dq[KNN]; int iq[KNN];
#pragma unroll
  for (int s = 0; s < KNN; ++s) { dq[s] = 3.4e38f; iq[s] = 0; }
  for (int j = 0; j < Nk; ++j) {
    float4 kk = keys[j];
    float qk = qx*kk.x + qy*kk.y + qz*kk.z;
    float d2 = q2 + kk.w - 2.0f*qk;
    if (d2 < dq[KNN-1]) {
      float cd = d2; int ci = j;
#pragma unroll
      for (int s = 0; s < KNN; ++s) {
        bool sw = cd < dq[s];
        float td = dq[s]; int ti = iq[s];
        dq[s] = sw ? cd : dq[s];
        iq[s] = sw ? ci : iq[s];
        cd = sw ? td : cd;
        ci = sw ? ti : ci;
      }
    }
  }
  int* op = idx + (size_t)(b*Nq + q)*KNN;
#pragma unroll
  for (int s = 0; s < KNN; ++s) op[s] = iq[s];
}

// ---------------- FPS: one block per batch, dist in registers -------------
template<int P>
__global__ __launch_bounds__(256) void fps_kernel(const float* __restrict__ xyz,
    int np, int* __restrict__ fidx) {
  constexpr int NN = P * 256;
  int b = blockIdx.x;
  int tid = threadIdx.x;
  float px[P], py[P], pz[P], dl[P];
#pragma unroll
  for (int i = 0; i < P; ++i) {
    int p = tid + (i << 8);
    const float* pp = xyz + (size_t)(b*NN + p)*3;
    px[i] = pp[0]; py[i] = pp[1]; pz[i] = pp[2];
    dl[i] = 1e10f;
  }
  __shared__ int s_far;
  __shared__ float s_bv[4];
  __shared__ int s_bi[4];
  if (tid == 0) s_far = 0;
  __syncthreads();
  for (int t = 0; t < np; ++t) {
    int far = s_far;
    if (tid == 0) fidx[b*np + t] = far;
    const float* cp = xyz + (size_t)(b*NN + far)*3;
    float cx = cp[0], cy = cp[1], cz = cp[2];
    float bv = -1.0f; int bi = 0;
#pragma unroll
    for (int i = 0; i < P; ++i) {
      float dx = __fsub_rn(px[i], cx);
      float dy = __fsub_rn(py[i], cy);
      float dz = __fsub_rn(pz[i], cz);
      float d = __fadd_rn(__fadd_rn(__fmul_rn(dx,dx), __fmul_rn(dy,dy)), __fmul_rn(dz,dz));
      dl[i] = fminf(dl[i], d);
      if (dl[i] > bv) { bv = dl[i]; bi = tid + (i << 8); }
    }
#pragma unroll
    for (int off = 32; off > 0; off >>= 1) {
      float ov = __shfl_down(bv, off);
      int oi = __shfl_down(bi, off);
      if (ov > bv || (ov == bv && oi < bi)) { bv = ov; bi = oi; }
    }
    int wid = tid >> 6;
    if ((tid & 63) == 0) { s_bv[wid] = bv; s_bi[wid] = bi; }
    __syncthreads();
    if (tid == 0) {
      float fv = s_bv[0]; int fi = s_bi[0];
#pragma unroll
      for (int w = 1; w < 4; ++w) {
        if (s_bv[w] > fv || (s_bv[w] == fv && s_bi[w] < fi)) { fv = s_bv[w]; fi = s_bi[w]; }
      }
      s_far = fi;
    }
    __syncthreads();
  }
}

// ---------------- gather coor_q / f_q by FPS indices ----------------------
__global__ __launch_bounds__(256) void gather_kernel(const float* __restrict__ coor,
    const float* __restrict__ f, int Nsrc, int C, const int* __restrict__ fidx,
    int np, float* __restrict__ coor_q, float* __restrict__ f_q) {
  int i = blockIdx.x * 256 + threadIdx.x;
  if (i >= BB * np) return;
  int b = i / np;
  int src = fidx[i];
  const float* cs = coor + (size_t)(b*Nsrc + src)*3;
  coor_q[i*3+0] = cs[0]; coor_q[i*3+1] = cs[1]; coor_q[i*3+2] = cs[2];
  const float* fs = f + (size_t)(b*Nsrc + src)*C;
  float* fd = f_q + (size_t)i*C;
  for (int c = 0; c < C; ++c) fd[c] = fs[c];
}

// ---------------- base[b,q,o] = sum_c (w[o,C+c]-w[o,c]) * xq[c] -----------
template<int C, int O>
__global__ __launch_bounds__(256) void base_kernel(const float* __restrict__ fq,
    const float* __restrict__ w, int Nq, float* __restrict__ base) {
  int i = blockIdx.x * 256 + threadIdx.x;
  if (i >= BB * Nq * O) return;
  int o = i % O;
  int bq = i / O;
  const float* fr = fq + (size_t)bq * C;
  const float* wr = w + (size_t)o * 2 * C;
  float acc = 0.f;
#pragma unroll
  for (int c = 0; c < C; ++c) acc += (wr[C + c] - wr[c]) * fr[c];
  base[i] = acc;
}

// ---------------- group-norm stats: one block per (b, group) --------------
template<int C, int O>
__global__ __launch_bounds__(256) void stats_kernel(const float* __restrict__ fsrc, int Nsrc,
    const int* __restrict__ idx, int Nq, const float* __restrict__ base,
    const float* __restrict__ w, float* __restrict__ stats) {
  constexpr int Og = O / 4;
  __shared__ float wl[Og * C];
  __shared__ double rs[256], rs2[256];
  int b = blockIdx.x >> 2;
  int g = blockIdx.x & 3;
  for (int t = threadIdx.x; t < Og * C; t += 256) {
    int o = g*Og + t / C; int c = t % C;
    wl[t] = w[(size_t)o*2*C + c];
  }
  __syncthreads();
  double s = 0.0, s2 = 0.0;
  int total = Nq * KNN;
  for (int e = threadIdx.x; e < total; e += 256) {
    int q = e >> 4, k = e & 15;
    int src = idx[(size_t)(b*Nq + q)*KNN + k];
    const float* fr = fsrc + (size_t)(b*Nsrc + src)*C;
    float ft[C];
#pragma unroll
    for (int c = 0; c < C; ++c) ft[c] = fr[c];
    const float* bp = base + (size_t)(b*Nq + q)*O + g*Og;
    for (int oo = 0; oo < Og; ++oo) {
      float acc = bp[oo];
      const float* wo = &wl[oo*C];
#pragma unroll
      for (int c = 0; c < C; ++c) acc += wo[c] * ft[c];
      s += acc;
      s2 += (double)acc * (double)acc;
    }
  }
  rs[threadIdx.x] = s; rs2[threadIdx.x] = s2;
  __syncthreads();
  for (int off = 128; off > 0; off >>= 1) {
    if (threadIdx.x < off) {
      rs[threadIdx.x] += rs[threadIdx.x+off];
      rs2[threadIdx.x] += rs2[threadIdx.x+off];
    }
    __syncthreads();
  }
  if (threadIdx.x == 0) {
    double cnt = (double)Og * (double)Nq * (double)KNN;
    double mu = rs[0] / cnt;
    double var = rs2[0] / cnt - mu*mu;
    stats[blockIdx.x*2 + 0] = (float)mu;
    stats[blockIdx.x*2 + 1] = (float)var;
  }
}

// ---------------- finalize: y -> GN -> lrelu -> max over k ----------------
template<int C, int O>
__global__ __launch_bounds__(64) void final_kernel(const float* __restrict__ fsrc, int Nsrc,
    const int* __restrict__ idx, int Nq, const float* __restrict__ base,
    const float* __restrict__ w, const float* __restrict__ stats,
    const float* __restrict__ gamma, const float* __restrict__ beta,
    float* __restrict__ fout) {
  constexpr int Og = O / 4;
  __shared__ float ft[KNN][C];
  int bq = blockIdx.x;
  int b = bq / Nq;
  const int* ip = idx + (size_t)bq * KNN;
  for (int t = threadIdx.x; t < KNN * C; t += 64) {
    int k = t / C, c = t % C;
    ft[k][c] = fsrc[(size_t)(b*Nsrc + ip[k])*C + c];
  }
  __syncthreads();
  for (int o = threadIdx.x; o < O; o += 64) {
    int g = o / Og;
    float mu  = stats[(b*4+g)*2 + 0];
    float var = stats[(b*4+g)*2 + 1];
    float rsv = 1.0f / sqrtf(var + EPSV);
    float ga = gamma[o], be = beta[o];
    float wr[C];
    const float* wp = w + (size_t)o*2*C;
#pragma unroll
    for (int c = 0; c < C; ++c) wr[c] = wp[c];
    float bs = base[(size_t)bq*O + o];
    float m = -3.4e38f;
    for (int k = 0; k < KNN; ++k) {
      float acc = bs;
#pragma unroll
      for (int c = 0; c < C; ++c) acc += wr[c] * ft[k][c];
      float xn = (acc - mu) * rsv;
      float yv = xn*ga + be;
      yv = yv > 0.f ? yv : LEAK*yv;
      m = fmaxf(m, yv);
    }
    fout[(size_t)bq*O + o] = m;
  }
}

extern "C" void kernel_launch(void* const* d_in, const int* in_sizes, int n_in,
                              void* d_out, int out_size, void* d_ws, size_t ws_size,
                              hipStream_t stream) {
  const float* x    = (const float*)d_in[0];
  const float* w_in = (const float*)d_in[3];
  const float* b_in = (const float*)d_in[4];
  const float* w1 = (const float*)d_in[5];
  const float* g1 = (const float*)d_in[6];
  const float* be1= (const float*)d_in[7];
  const float* w2 = (const float*)d_in[8];
  const float* g2 = (const float*)d_in[9];
  const float* be2= (const float*)d_in[10];
  const float* w3 = (const float*)d_in[11];
  const float* g3 = (const float*)d_in[12];
  const float* be3= (const float*)d_in[13];
  const float* w4 = (const float*)d_in[14];
  const float* g4 = (const float*)d_in[15];
  const float* be4= (const float*)d_in[16];
  float* out = (float*)d_out;
  (void)in_sizes; (void)n_in; (void)out_size; (void)ws_size;

  char* ws = (char*)d_ws;
  size_t off = 0;
  auto alloc = [&](size_t count) {
    void* p = ws + off;
    off += (count * 4 + 255) & ~(size_t)255;
    return p;
  };
  float* f0    = (float*)alloc(16*2048*8);
  float* f1    = (float*)alloc(16*2048*32);
  float* f2    = (float*)alloc(16*512*64);
  float* f3    = (float*)alloc(16*512*64);
  float* fq1   = (float*)alloc(16*512*32);
  float* fq2   = (float*)alloc(16*128*64);
  float* cq1   = (float*)alloc(16*512*3);
  float* basep = (float*)alloc(16*2048*32);
  float* stats = (float*)alloc(16*4*2);
  int* idx1    = (int*)alloc(16*2048*16);
  int* idx2    = (int*)alloc(16*512*16);
  int* idx3    = (int*)alloc(16*512*16);
  int* idx4    = (int*)alloc(16*128*16);
  int* fidx1   = (int*)alloc(16*512);
  int* fidx2   = (int*)alloc(16*128);

  float* cq2 = out;              // (16,128,3)
  float* f4  = out + 16*128*3;   // (16,128,128)

  f0_kernel<<<(16*2048)/256, 256, 0, stream>>>(x, w_in, b_in, f0);

  // ---- layer 1: C=8 -> O=32, Nq=2048, keys=x (2048) ----
  knn_kernel<<<16*8, 256, 0, stream>>>(x, 2048, x, 2048, idx1);
  base_kernel<8,32><<<(16*2048*32)/256, 256, 0, stream>>>(f0, w1, 2048, basep);
  stats_kernel<8,32><<<64, 256, 0, stream>>>(f0, 2048, idx1, 2048, basep, w1, stats);
  final_kernel<8,32><<<16*2048, 64, 0, stream>>>(f0, 2048, idx1, 2048, basep, w1, stats, g1, be1, f1);

  // ---- fps 2048 -> 512 ----
  fps_kernel<8><<<16, 256, 0, stream>>>(x, 512, fidx1);
  gather_kernel<<<(16*512)/256, 256, 0, stream>>>(x, f1, 2048, 32, fidx1, 512, cq1, fq1);

  // ---- layer 2: C=32 -> O=64, Nq=512, keys=x (2048) ----
  knn_kernel<<<16*2, 256, 0, stream>>>(cq1, 512, x, 2048, idx2);
  base_kernel<32,64><<<(16*512*64)/256, 256, 0, stream>>>(fq1, w2, 512, basep);
  stats_kernel<32,64><<<64, 256, 0, stream>>>(f1, 2048, idx2, 512, basep, w2, stats);
  final_kernel<32,64><<<16*512, 64, 0, stream>>>(f1, 2048, idx2, 512, basep, w2, stats, g2, be2, f2);

  // ---- layer 3: C=64 -> O=64, Nq=512, keys=cq1 (512) ----
  knn_kernel<<<16*2, 256, 0, stream>>>(cq1, 512, cq1, 512, idx3);
  base_kernel<64,64><<<(16*512*64)/256, 256, 0, stream>>>(f2, w3, 512, basep);
  stats_kernel<64,64><<<64, 256, 0, stream>>>(f2, 512, idx3, 512, basep, w3, stats);
  final_kernel<64,64><<<16*512, 64, 0, stream>>>(f2, 512, idx3, 512, basep, w3, stats, g3, be3, f3);

  // ---- fps 512 -> 128 ----
  fps_kernel<2><<<16, 256, 0, stream>>>(cq1, 128, fidx2);
  gather_kernel<<<(16*128)/256, 256, 0, stream>>>(cq1, f3, 512, 64, fidx2, 128, cq2, fq2);

  // ---- layer 4: C=64 -> O=128, Nq=128, keys=cq1 (512) ----
  knn_kernel<<<16*1, 256, 0, stream>>>(cq2, 128, cq1, 512, idx4);
  base_kernel<64,128><<<(16*128*128)/256, 256, 0, stream>>>(fq2, w4, 128, basep);
  stats_kernel<64,128><<<64, 256, 0, stream>>>(f3, 512, idx4, 128, basep, w4, stats);
  final_kernel<64,128><<<16*128, 64, 0, stream>>>(f3, 512, idx4, 128, basep, w4, stats, g4, be4, f4);
}

// Round 2
// 1864.922 us; speedup vs baseline: 2.1600x; 2.1600x over previous
//
#include <hip/hip_runtime.h>

#define KNN 16
static constexpr int BB = 16;
static constexpr float LEAK = 0.2f;
static constexpr float EPSV = 1e-5f;

// ---------------- f0 = w_in @ coor + b_in  (point-major) ----------------
__global__ __launch_bounds__(256) void f0_kernel(const float* __restrict__ x,
    const float* __restrict__ w_in, const float* __restrict__ b_in,
    float* __restrict__ f0) {
  int i = blockIdx.x * 256 + threadIdx.x;
  if (i >= BB * 2048) return;
  float px = x[i*3+0], py = x[i*3+1], pz = x[i*3+2];
#pragma unroll
  for (int o = 0; o < 8; ++o) {
    f0[i*8+o] = w_in[o*3+0]*px + w_in[o*3+1]*py + w_in[o*3+2]*pz + b_in[o];
  }
}

// ---------------- kNN split-K: per-(qchunk,kchunk) partial top-16 ----------
// part[((b*Nq+q)*KC + c)*16 + s] = (dist, idx) sorted ascending within chunk.
__global__ __launch_bounds__(256) void knn_part_kernel(
    const float* __restrict__ qxyz, int Nq,
    const float* __restrict__ kxyz, int Nk,
    int KC, float2* __restrict__ part) {
  __shared__ float4 keys[1024];
  int nqb = (Nq + 255) >> 8;
  int bid = blockIdx.x;
  int c  = bid % KC;
  int qb = (bid / KC) % nqb;
  int b  = bid / (KC * nqb);
  int nkc = Nk / KC;              // keys per chunk (<=1024, multiple of 8)
  int kbase = c * nkc;
  for (int j = threadIdx.x; j < nkc; j += 256) {
    const float* kp = kxyz + (size_t)(b*Nk + kbase + j)*3;
    float kx = kp[0], ky = kp[1], kz = kp[2];
    keys[j] = make_float4(kx, ky, kz, kx*kx + ky*ky + kz*kz);
  }
  __syncthreads();
  int q = (qb << 8) + threadIdx.x;
  if (q >= Nq) return;
  const float* qp = qxyz + (size_t)(b*Nq + q)*3;
  float qx = qp[0], qy = qp[1], qz = qp[2];
  float q2 = qx*qx + qy*qy + qz*qz;
  float dq[KNN]; int iq[KNN];
#pragma unroll
  for (int s = 0; s < KNN; ++s) { dq[s] = 3.4e38f; iq[s] = 0; }
  for (int j0 = 0; j0 < nkc; j0 += 8) {
    float d2v[8];
#pragma unroll
    for (int u = 0; u < 8; ++u) {
      float4 kk = keys[j0 + u];
      float qk = qx*kk.x + qy*kk.y + qz*kk.z;
      d2v[u] = q2 + kk.w - 2.0f*qk;
    }
#pragma unroll
    for (int u = 0; u < 8; ++u) {
      if (d2v[u] < dq[KNN-1]) {
        float cd = d2v[u]; int ci = kbase + j0 + u;
#pragma unroll
        for (int s = 0; s < KNN; ++s) {
          bool sw = cd < dq[s];
          float td = dq[s]; int ti = iq[s];
          dq[s] = sw ? cd : dq[s];
          iq[s] = sw ? ci : iq[s];
          cd = sw ? td : cd;
          ci = sw ? ti : ci;
        }
      }
    }
  }
  float2* op = part + ((size_t)(b*Nq + q)*KC + c)*KNN;
#pragma unroll
  for (int s = 0; s < KNN; ++s) op[s] = make_float2(dq[s], __int_as_float(iq[s]));
}

// ---------------- merge KC*16 candidates -> final top-16 indices ----------
__global__ __launch_bounds__(256) void knn_merge_kernel(
    const float2* __restrict__ part, int KC, int total, int* __restrict__ idx) {
  int i = blockIdx.x * 256 + threadIdx.x;
  if (i >= total) return;
  const float2* p = part + (size_t)i * KC * KNN;
  float dq[KNN]; int iq[KNN];
#pragma unroll
  for (int s = 0; s < KNN; ++s) { dq[s] = 3.4e38f; iq[s] = 0; }
  int nc = KC * KNN;
  for (int t = 0; t < nc; ++t) {
    float2 cp = p[t];
    float cd = cp.x;
    if (cd < dq[KNN-1]) {
      int ci = __float_as_int(cp.y);
#pragma unroll
      for (int s = 0; s < KNN; ++s) {
        bool sw = cd < dq[s];
        float td = dq[s]; int ti = iq[s];
        dq[s] = sw ? cd : dq[s];
        iq[s] = sw ? ci : iq[s];
        cd = sw ? td : cd;
        ci = sw ? ti : ci;
      }
    }
  }
  int* op = idx + (size_t)i * KNN;
#pragma unroll
  for (int s = 0; s < KNN; ++s) op[s] = iq[s];
}

// ---------------- FPS: one block per batch, points in LDS, 1 sync/iter ----
template<int P>
__global__ __launch_bounds__(256) void fps_kernel(const float* __restrict__ xyz,
    int np, int* __restrict__ fidx) {
  constexpr int NN = P * 256;
  __shared__ float sx[NN], sy[NN], sz[NN];
  __shared__ float s_bv[2][4];
  __shared__ int s_bi[2][4];
  int b = blockIdx.x;
  int tid = threadIdx.x;
  float px[P], py[P], pz[P], dl[P];
#pragma unroll
  for (int i = 0; i < P; ++i) {
    int p = tid + (i << 8);
    const float* pp = xyz + (size_t)(b*NN + p)*3;
    px[i] = pp[0]; py[i] = pp[1]; pz[i] = pp[2];
    sx[p] = px[i]; sy[p] = py[i]; sz[p] = pz[i];
    dl[i] = 1e10f;
  }
  __syncthreads();
  int far = 0;
  for (int t = 0; t < np; ++t) {
    if (tid == 0) fidx[b*np + t] = far;
    float cx = sx[far], cy = sy[far], cz = sz[far];  // LDS broadcast
    float bv = -1.0f; int bi = 0;
#pragma unroll
    for (int i = 0; i < P; ++i) {
      float dx = __fsub_rn(px[i], cx);
      float dy = __fsub_rn(py[i], cy);
      float dz = __fsub_rn(pz[i], cz);
      float d = __fadd_rn(__fadd_rn(__fmul_rn(dx,dx), __fmul_rn(dy,dy)), __fmul_rn(dz,dz));
      dl[i] = fminf(dl[i], d);
      if (dl[i] > bv) { bv = dl[i]; bi = tid + (i << 8); }
    }
#pragma unroll
    for (int off = 32; off > 0; off >>= 1) {
      float ov = __shfl_down(bv, off);
      int oi = __shfl_down(bi, off);
      if (ov > bv || (ov == bv && oi < bi)) { bv = ov; bi = oi; }
    }
    int buf = t & 1;
    if ((tid & 63) == 0) { s_bv[buf][tid >> 6] = bv; s_bi[buf][tid >> 6] = bi; }
    __syncthreads();
    float fv = s_bv[buf][0]; int fi = s_bi[buf][0];
#pragma unroll
    for (int w = 1; w < 4; ++w) {
      if (s_bv[buf][w] > fv || (s_bv[buf][w] == fv && s_bi[buf][w] < fi)) {
        fv = s_bv[buf][w]; fi = s_bi[buf][w];
      }
    }
    far = fi;   // uniform across all threads; next iter writes other buffer
  }
}

// ---------------- gather coor_q / f_q by FPS indices ----------------------
__global__ __launch_bounds__(256) void gather_kernel(const float* __restrict__ coor,
    const float* __restrict__ f, int Nsrc, int C, const int* __restrict__ fidx,
    int np, float* __restrict__ coor_q, float* __restrict__ f_q) {
  int i = blockIdx.x * 256 + threadIdx.x;
  if (i >= BB * np) return;
  int b = i / np;
  int src = fidx[i];
  const float* cs = coor + (size_t)(b*Nsrc + src)*3;
  coor_q[i*3+0] = cs[0]; coor_q[i*3+1] = cs[1]; coor_q[i*3+2] = cs[2];
  const float* fs = f + (size_t)(b*Nsrc + src)*C;
  float* fd = f_q + (size_t)i*C;
  for (int c = 0; c < C; ++c) fd[c] = fs[c];
}

// ---------------- base[b,q,o] = sum_c (w[o,C+c]-w[o,c]) * xq[c] -----------
template<int C, int O>
__global__ __launch_bounds__(256) void base_kernel(const float* __restrict__ fq,
    const float* __restrict__ w, int Nq, float* __restrict__ base) {
  int i = blockIdx.x * 256 + threadIdx.x;
  if (i >= BB * Nq * O) return;
  int o = i % O;
  int bq = i / O;
  const float* fr = fq + (size_t)bq * C;
  const float* wr = w + (size_t)o * 2 * C;
  float acc = 0.f;
#pragma unroll
  for (int c = 0; c < C; ++c) acc += (wr[C + c] - wr[c]) * fr[c];
  base[i] = acc;
}

// ---------------- group-norm stats: one block per (b, group) --------------
template<int C, int O>
__global__ __launch_bounds__(256) void stats_kernel(const float* __restrict__ fsrc, int Nsrc,
    const int* __restrict__ idx, int Nq, const float* __restrict__ base,
    const float* __restrict__ w, float* __restrict__ stats) {
  constexpr int Og = O / 4;
  __shared__ float wl[Og * C];
  __shared__ double rs[256], rs2[256];
  int b = blockIdx.x >> 2;
  int g = blockIdx.x & 3;
  for (int t = threadIdx.x; t < Og * C; t += 256) {
    int o = g*Og + t / C; int c = t % C;
    wl[t] = w[(size_t)o*2*C + c];
  }
  __syncthreads();
  double s = 0.0, s2 = 0.0;
  int total = Nq * KNN;
  for (int e = threadIdx.x; e < total; e += 256) {
    int q = e >> 4, k = e & 15;
    int src = idx[(size_t)(b*Nq + q)*KNN + k];
    const float* fr = fsrc + (size_t)(b*Nsrc + src)*C;
    float ft[C];
#pragma unroll
    for (int c = 0; c < C; ++c) ft[c] = fr[c];
    const float* bp = base + (size_t)(b*Nq + q)*O + g*Og;
    for (int oo = 0; oo < Og; ++oo) {
      float acc = bp[oo];
      const float* wo = &wl[oo*C];
#pragma unroll
      for (int c = 0; c < C; ++c) acc += wo[c] * ft[c];
      s += acc;
      s2 += (double)acc * (double)acc;
    }
  }
  rs[threadIdx.x] = s; rs2[threadIdx.x] = s2;
  __syncthreads();
  for (int off = 128; off > 0; off >>= 1) {
    if (threadIdx.x < off) {
      rs[threadIdx.x] += rs[threadIdx.x+off];
      rs2[threadIdx.x] += rs2[threadIdx.x+off];
    }
    __syncthreads();
  }
  if (threadIdx.x == 0) {
    double cnt = (double)Og * (double)Nq * (double)KNN;
    double mu = rs[0] / cnt;
    double var = rs2[0] / cnt - mu*mu;
    stats[blockIdx.x*2 + 0] = (float)mu;
    stats[blockIdx.x*2 + 1] = (float)var;
  }
}

// ---------------- finalize: y -> GN -> lrelu -> max over k ----------------
template<int C, int O>
__global__ __launch_bounds__(64) void final_kernel(const float* __restrict__ fsrc, int Nsrc,
    const int* __restrict__ idx, int Nq, const float* __restrict__ base,
    const float* __restrict__ w, const float* __restrict__ stats,
    const float* __restrict__ gamma, const float* __restrict__ beta,
    float* __restrict__ fout) {
  constexpr int Og = O / 4;
  __shared__ float ft[KNN][C];
  int bq = blockIdx.x;
  int b = bq / Nq;
  const int* ip = idx + (size_t)bq * KNN;
  for (int t = threadIdx.x; t < KNN * C; t += 64) {
    int k = t / C, c = t % C;
    ft[k][c] = fsrc[(size_t)(b*Nsrc + ip[k])*C + c];
  }
  __syncthreads();
  for (int o = threadIdx.x; o < O; o += 64) {
    int g = o / Og;
    float mu  = stats[(b*4+g)*2 + 0];
    float var = stats[(b*4+g)*2 + 1];
    float rsv = 1.0f / sqrtf(var + EPSV);
    float ga = gamma[o], be = beta[o];
    float wr[C];
    const float* wp = w + (size_t)o*2*C;
#pragma unroll
    for (int c = 0; c < C; ++c) wr[c] = wp[c];
    float bs = base[(size_t)bq*O + o];
    float m = -3.4e38f;
    for (int k = 0; k < KNN; ++k) {
      float acc = bs;
#pragma unroll
      for (int c = 0; c < C; ++c) acc += wr[c] * ft[k][c];
      float xn = (acc - mu) * rsv;
      float yv = xn*ga + be;
      yv = yv > 0.f ? yv : LEAK*yv;
      m = fmaxf(m, yv);
    }
    fout[(size_t)bq*O + o] = m;
  }
}

extern "C" void kernel_launch(void* const* d_in, const int* in_sizes, int n_in,
                              void* d_out, int out_size, void* d_ws, size_t ws_size,
                              hipStream_t stream) {
  const float* x    = (const float*)d_in[0];
  const float* w_in = (const float*)d_in[3];
  const float* b_in = (const float*)d_in[4];
  const float* w1 = (const float*)d_in[5];
  const float* g1 = (const float*)d_in[6];
  const float* be1= (const float*)d_in[7];
  const float* w2 = (const float*)d_in[8];
  const float* g2 = (const float*)d_in[9];
  const float* be2= (const float*)d_in[10];
  const float* w3 = (const float*)d_in[11];
  const float* g3 = (const float*)d_in[12];
  const float* be3= (const float*)d_in[13];
  const float* w4 = (const float*)d_in[14];
  const float* g4 = (const float*)d_in[15];
  const float* be4= (const float*)d_in[16];
  float* out = (float*)d_out;
  (void)in_sizes; (void)n_in; (void)out_size; (void)ws_size;

  char* ws = (char*)d_ws;
  size_t off = 0;
  auto alloc = [&](size_t count) {
    void* p = ws + off;
    off += (count * 4 + 255) & ~(size_t)255;
    return p;
  };
  float* f0    = (float*)alloc(16*2048*8);
  float* f1    = (float*)alloc(16*2048*32);
  float* f2    = (float*)alloc(16*512*64);
  float* f3    = (float*)alloc(16*512*64);
  float* fq1   = (float*)alloc(16*512*32);
  float* fq2   = (float*)alloc(16*128*64);
  float* cq1   = (float*)alloc(16*512*3);
  float* basep = (float*)alloc(16*2048*32);
  float* stats = (float*)alloc(16*4*2);
  int* idx1    = (int*)alloc(16*2048*16);
  int* idx2    = (int*)alloc(16*512*16);
  int* idx3    = (int*)alloc(16*512*16);
  int* idx4    = (int*)alloc(16*128*16);
  int* fidx1   = (int*)alloc(16*512);
  int* fidx2   = (int*)alloc(16*128);
  float2* part = (float2*)alloc(2 * 16*2048*2*16);  // 8 MB, reused per layer

  float* cq2 = out;              // (16,128,3)
  float* f4  = out + 16*128*3;   // (16,128,128)

  f0_kernel<<<(16*2048)/256, 256, 0, stream>>>(x, w_in, b_in, f0);

  // ---- layer 1: C=8 -> O=32, Nq=2048, keys=x (2048) ----
  knn_part_kernel<<<16*8*2, 256, 0, stream>>>(x, 2048, x, 2048, 2, part);
  knn_merge_kernel<<<(16*2048)/256, 256, 0, stream>>>(part, 2, 16*2048, idx1);
  base_kernel<8,32><<<(16*2048*32)/256, 256, 0, stream>>>(f0, w1, 2048, basep);
  stats_kernel<8,32><<<64, 256, 0, stream>>>(f0, 2048, idx1, 2048, basep, w1, stats);
  final_kernel<8,32><<<16*2048, 64, 0, stream>>>(f0, 2048, idx1, 2048, basep, w1, stats, g1, be1, f1);

  // ---- fps 2048 -> 512 ----
  fps_kernel<8><<<16, 256, 0, stream>>>(x, 512, fidx1);
  gather_kernel<<<(16*512)/256, 256, 0, stream>>>(x, f1, 2048, 32, fidx1, 512, cq1, fq1);

  // ---- layer 2: C=32 -> O=64, Nq=512, keys=x (2048) ----
  knn_part_kernel<<<16*2*8, 256, 0, stream>>>(cq1, 512, x, 2048, 8, part);
  knn_merge_kernel<<<(16*512)/256, 256, 0, stream>>>(part, 8, 16*512, idx2);
  base_kernel<32,64><<<(16*512*64)/256, 256, 0, stream>>>(fq1, w2, 512, basep);
  stats_kernel<32,64><<<64, 256, 0, stream>>>(f1, 2048, idx2, 512, basep, w2, stats);
  final_kernel<32,64><<<16*512, 64, 0, stream>>>(f1, 2048, idx2, 512, basep, w2, stats, g2, be2, f2);

  // ---- layer 3: C=64 -> O=64, Nq=512, keys=cq1 (512) ----
  knn_part_kernel<<<16*2*8, 256, 0, stream>>>(cq1, 512, cq1, 512, 8, part);
  knn_merge_kernel<<<(16*512)/256, 256, 0, stream>>>(part, 8, 16*512, idx3);
  base_kernel<64,64><<<(16*512*64)/256, 256, 0, stream>>>(f2, w3, 512, basep);
  stats_kernel<64,64><<<64, 256, 0, stream>>>(f2, 512, idx3, 512, basep, w3, stats);
  final_kernel<64,64><<<16*512, 64, 0, stream>>>(f2, 512, idx3, 512, basep, w3, stats, g3, be3, f3);

  // ---- fps 512 -> 128 ----
  fps_kernel<2><<<16, 256, 0, stream>>>(cq1, 128, fidx2);
  gather_kernel<<<(16*128)/256, 256, 0, stream>>>(cq1, f3, 512, 64, fidx2, 128, cq2, fq2);

  // ---- layer 4: C=64 -> O=128, Nq=128, keys=cq1 (512) ----
  knn_part_kernel<<<16*1*8, 256, 0, stream>>>(cq2, 128, cq1, 512, 8, part);
  knn_merge_kernel<<<(16*128 + 255)/256, 256, 0, stream>>>(part, 8, 16*128, idx4);
  base_kernel<64,128><<<(16*128*128)/256, 256, 0, stream>>>(fq2, w4, 128, basep);
  stats_kernel<64,128><<<64, 256, 0, stream>>>(f3, 512, idx4, 128, basep, w4, stats);
  final_kernel<64,128><<<16*128, 64, 0, stream>>>(f3, 512, idx4, 128, basep, w4, stats, g4, be4, f4);
}

// Round 3
// 1536.080 us; speedup vs baseline: 2.6224x; 1.2141x over previous
//
#include <hip/hip_runtime.h>

#define KNN 16
static constexpr int BB = 16;
static constexpr float LEAK = 0.2f;
static constexpr float EPSV = 1e-5f;

// ---------------- f0 = w_in @ coor + b_in  (point-major) ----------------
__global__ __launch_bounds__(256) void f0_kernel(const float* __restrict__ x,
    const float* __restrict__ w_in, const float* __restrict__ b_in,
    float* __restrict__ f0) {
  int i = blockIdx.x * 256 + threadIdx.x;
  if (i >= BB * 2048) return;
  float px = x[i*3+0], py = x[i*3+1], pz = x[i*3+2];
#pragma unroll
  for (int o = 0; o < 8; ++o) {
    f0[i*8+o] = w_in[o*3+0]*px + w_in[o*3+1]*py + w_in[o*3+2]*pz + b_in[o];
  }
}

// ---------------- kNN split-K: per-(qchunk,kchunk) partial top-16 ----------
__global__ __launch_bounds__(256) void knn_part_kernel(
    const float* __restrict__ qxyz, int Nq,
    const float* __restrict__ kxyz, int Nk,
    int KC, float2* __restrict__ part) {
  __shared__ float4 keys[1024];
  int nqb = (Nq + 255) >> 8;
  int bid = blockIdx.x;
  int c  = bid % KC;
  int qb = (bid / KC) % nqb;
  int b  = bid / (KC * nqb);
  int nkc = Nk / KC;              // keys per chunk (<=1024, multiple of 8)
  int kbase = c * nkc;
  for (int j = threadIdx.x; j < nkc; j += 256) {
    const float* kp = kxyz + (size_t)(b*Nk + kbase + j)*3;
    float kx = kp[0], ky = kp[1], kz = kp[2];
    keys[j] = make_float4(kx, ky, kz, kx*kx + ky*ky + kz*kz);
  }
  __syncthreads();
  int q = (qb << 8) + threadIdx.x;
  if (q >= Nq) return;
  const float* qp = qxyz + (size_t)(b*Nq + q)*3;
  float qx = qp[0], qy = qp[1], qz = qp[2];
  float q2 = qx*qx + qy*qy + qz*qz;
  float dq[KNN]; int iq[KNN];
#pragma unroll
  for (int s = 0; s < KNN; ++s) { dq[s] = 3.4e38f; iq[s] = 0; }
  for (int j0 = 0; j0 < nkc; j0 += 8) {
    float d2v[8];
#pragma unroll
    for (int u = 0; u < 8; ++u) {
      float4 kk = keys[j0 + u];
      float qk = qx*kk.x + qy*kk.y + qz*kk.z;
      d2v[u] = q2 + kk.w - 2.0f*qk;
    }
#pragma unroll
    for (int u = 0; u < 8; ++u) {
      if (d2v[u] < dq[KNN-1]) {
        float cd = d2v[u]; int ci = kbase + j0 + u;
#pragma unroll
        for (int s = 0; s < KNN; ++s) {
          bool sw = cd < dq[s];
          float td = dq[s]; int ti = iq[s];
          dq[s] = sw ? cd : dq[s];
          iq[s] = sw ? ci : iq[s];
          cd = sw ? td : cd;
          ci = sw ? ti : ci;
        }
      }
    }
  }
  float2* op = part + ((size_t)(b*Nq + q)*KC + c)*KNN;
#pragma unroll
  for (int s = 0; s < KNN; ++s) op[s] = make_float2(dq[s], __int_as_float(iq[s]));
}

// ---------------- merge KC*16 candidates -> final top-16 indices ----------
__global__ __launch_bounds__(256) void knn_merge_kernel(
    const float2* __restrict__ part, int KC, int total, int* __restrict__ idx) {
  int i = blockIdx.x * 256 + threadIdx.x;
  if (i >= total) return;
  const float2* p = part + (size_t)i * KC * KNN;
  float dq[KNN]; int iq[KNN];
#pragma unroll
  for (int s = 0; s < KNN; ++s) { dq[s] = 3.4e38f; iq[s] = 0; }
  int nc = KC * KNN;
  for (int t = 0; t < nc; ++t) {
    float2 cp = p[t];
    float cd = cp.x;
    if (cd < dq[KNN-1]) {
      int ci = __float_as_int(cp.y);
#pragma unroll
      for (int s = 0; s < KNN; ++s) {
        bool sw = cd < dq[s];
        float td = dq[s]; int ti = iq[s];
        dq[s] = sw ? cd : dq[s];
        iq[s] = sw ? ci : iq[s];
        cd = sw ? td : cd;
        ci = sw ? ti : ci;
      }
    }
  }
  int* op = idx + (size_t)i * KNN;
#pragma unroll
  for (int s = 0; s < KNN; ++s) op[s] = iq[s];
}

// ---------------- FPS: packed-u64 argmax, DPP wave reduce -----------------
// key = (float_bits(dist) << 32) | ~idx : u64 max == (max dist, min idx).
__device__ __forceinline__ unsigned long long fps_max64(unsigned long long a,
                                                        unsigned long long b) {
  return a > b ? a : b;
}
template<int CTRL>
__device__ __forceinline__ unsigned long long fps_dpp_u64(unsigned long long v) {
  unsigned lo = (unsigned)__builtin_amdgcn_update_dpp(0, (int)(unsigned)(v & 0xFFFFFFFFull),
                                                      CTRL, 0xF, 0xF, false);
  unsigned hi = (unsigned)__builtin_amdgcn_update_dpp(0, (int)(unsigned)(v >> 32),
                                                      CTRL, 0xF, 0xF, false);
  return ((unsigned long long)hi << 32) | lo;
}
template<int P>
__global__ __launch_bounds__(256) void fps_kernel(const float* __restrict__ xyz,
    int np, int* __restrict__ fidx) {
  constexpr int NN = P * 256;
  __shared__ float sx[NN], sy[NN], sz[NN];
  __shared__ unsigned long long s_key[2][4];
  int b = blockIdx.x;
  int tid = threadIdx.x;
  float px[P], py[P], pz[P], dl[P];
#pragma unroll
  for (int i = 0; i < P; ++i) {
    int p = tid + (i << 8);
    const float* pp = xyz + (size_t)(b*NN + p)*3;
    px[i] = pp[0]; py[i] = pp[1]; pz[i] = pp[2];
    sx[p] = px[i]; sy[p] = py[i]; sz[p] = pz[i];
    dl[i] = 1e10f;
  }
  __syncthreads();
  int far = 0;
  for (int t = 0; t < np; ++t) {
    if (tid == 0) fidx[b*np + t] = far;
    float cx = sx[far], cy = sy[far], cz = sz[far];  // uniform LDS broadcast
    float bv = -1.0f; int bi = 0;
#pragma unroll
    for (int i = 0; i < P; ++i) {
      float dx = __fsub_rn(px[i], cx);
      float dy = __fsub_rn(py[i], cy);
      float dz = __fsub_rn(pz[i], cz);
      float d = __fadd_rn(__fadd_rn(__fmul_rn(dx,dx), __fmul_rn(dy,dy)), __fmul_rn(dz,dz));
      dl[i] = fminf(dl[i], d);
      if (dl[i] > bv) { bv = dl[i]; bi = tid + (i << 8); }  // ascending i => min idx on ties
    }
    // pack: dist bits (>=0, order-monotonic) high, ~idx low
    unsigned long long k = ((unsigned long long)__float_as_uint(bv) << 32)
                         | (unsigned)(~bi);
    // wave64 max-reduce into lane 63 via DPP (VALU-latency, no LDS)
    k = fps_max64(k, fps_dpp_u64<0x111>(k));  // row_shr:1
    k = fps_max64(k, fps_dpp_u64<0x112>(k));  // row_shr:2
    k = fps_max64(k, fps_dpp_u64<0x114>(k));  // row_shr:4
    k = fps_max64(k, fps_dpp_u64<0x118>(k));  // row_shr:8
    k = fps_max64(k, fps_dpp_u64<0x142>(k));  // row_bcast:15
    k = fps_max64(k, fps_dpp_u64<0x143>(k));  // row_bcast:31
    unsigned wlo = (unsigned)__builtin_amdgcn_readlane((int)(unsigned)(k & 0xFFFFFFFFull), 63);
    unsigned whi = (unsigned)__builtin_amdgcn_readlane((int)(unsigned)(k >> 32), 63);
    int buf = t & 1;
    if ((tid & 63) == 0)
      s_key[buf][tid >> 6] = ((unsigned long long)whi << 32) | wlo;
    __syncthreads();
    unsigned long long best = s_key[buf][0];
    best = fps_max64(best, s_key[buf][1]);
    best = fps_max64(best, s_key[buf][2]);
    best = fps_max64(best, s_key[buf][3]);
    far = (int)(~(unsigned)(best & 0xFFFFFFFFull));  // uniform across block
  }
}

// ---------------- gather coor_q / f_q by FPS indices ----------------------
__global__ __launch_bounds__(256) void gather_kernel(const float* __restrict__ coor,
    const float* __restrict__ f, int Nsrc, int C, const int* __restrict__ fidx,
    int np, float* __restrict__ coor_q, float* __restrict__ f_q) {
  int i = blockIdx.x * 256 + threadIdx.x;
  if (i >= BB * np) return;
  int b = i / np;
  int src = fidx[i];
  const float* cs = coor + (size_t)(b*Nsrc + src)*3;
  coor_q[i*3+0] = cs[0]; coor_q[i*3+1] = cs[1]; coor_q[i*3+2] = cs[2];
  const float* fs = f + (size_t)(b*Nsrc + src)*C;
  float* fd = f_q + (size_t)i*C;
  for (int c = 0; c < C; ++c) fd[c] = fs[c];
}

// ---------------- base[b,q,o] = sum_c (w[o,C+c]-w[o,c]) * xq[c] -----------
template<int C, int O>
__global__ __launch_bounds__(256) void base_kernel(const float* __restrict__ fq,
    const float* __restrict__ w, int Nq, float* __restrict__ base) {
  int i = blockIdx.x * 256 + threadIdx.x;
  if (i >= BB * Nq * O) return;
  int o = i % O;
  int bq = i / O;
  const float* fr = fq + (size_t)bq * C;
  const float* wr = w + (size_t)o * 2 * C;
  float acc = 0.f;
#pragma unroll
  for (int c = 0; c < C; ++c) acc += (wr[C + c] - wr[c]) * fr[c];
  base[i] = acc;
}

// ---------------- group-norm stats: one block per (b, group) --------------
template<int C, int O>
__global__ __launch_bounds__(256) void stats_kernel(const float* __restrict__ fsrc, int Nsrc,
    const int* __restrict__ idx, int Nq, const float* __restrict__ base,
    const float* __restrict__ w, float* __restrict__ stats) {
  constexpr int Og = O / 4;
  __shared__ float wl[Og * C];
  __shared__ double rs[256], rs2[256];
  int b = blockIdx.x >> 2;
  int g = blockIdx.x & 3;
  for (int t = threadIdx.x; t < Og * C; t += 256) {
    int o = g*Og + t / C; int c = t % C;
    wl[t] = w[(size_t)o*2*C + c];
  }
  __syncthreads();
  double s = 0.0, s2 = 0.0;
  int total = Nq * KNN;
  for (int e = threadIdx.x; e < total; e += 256) {
    int q = e >> 4, k = e & 15;
    int src = idx[(size_t)(b*Nq + q)*KNN + k];
    const float* fr = fsrc + (size_t)(b*Nsrc + src)*C;
    float ft[C];
#pragma unroll
    for (int c = 0; c < C; ++c) ft[c] = fr[c];
    const float* bp = base + (size_t)(b*Nq + q)*O + g*Og;
    for (int oo = 0; oo < Og; ++oo) {
      float acc = bp[oo];
      const float* wo = &wl[oo*C];
#pragma unroll
      for (int c = 0; c < C; ++c) acc += wo[c] * ft[c];
      s += acc;
      s2 += (double)acc * (double)acc;
    }
  }
  rs[threadIdx.x] = s; rs2[threadIdx.x] = s2;
  __syncthreads();
  for (int off = 128; off > 0; off >>= 1) {
    if (threadIdx.x < off) {
      rs[threadIdx.x] += rs[threadIdx.x+off];
      rs2[threadIdx.x] += rs2[threadIdx.x+off];
    }
    __syncthreads();
  }
  if (threadIdx.x == 0) {
    double cnt = (double)Og * (double)Nq * (double)KNN;
    double mu = rs[0] / cnt;
    double var = rs2[0] / cnt - mu*mu;
    stats[blockIdx.x*2 + 0] = (float)mu;
    stats[blockIdx.x*2 + 1] = (float)var;
  }
}

// ---------------- finalize: y -> GN -> lrelu -> max over k ----------------
template<int C, int O>
__global__ __launch_bounds__(64) void final_kernel(const float* __restrict__ fsrc, int Nsrc,
    const int* __restrict__ idx, int Nq, const float* __restrict__ base,
    const float* __restrict__ w, const float* __restrict__ stats,
    const float* __restrict__ gamma, const float* __restrict__ beta,
    float* __restrict__ fout) {
  constexpr int Og = O / 4;
  __shared__ float ft[KNN][C];
  int bq = blockIdx.x;
  int b = bq / Nq;
  const int* ip = idx + (size_t)bq * KNN;
  for (int t = threadIdx.x; t < KNN * C; t += 64) {
    int k = t / C, c = t % C;
    ft[k][c] = fsrc[(size_t)(b*Nsrc + ip[k])*C + c];
  }
  __syncthreads();
  for (int o = threadIdx.x; o < O; o += 64) {
    int g = o / Og;
    float mu  = stats[(b*4+g)*2 + 0];
    float var = stats[(b*4+g)*2 + 1];
    float rsv = 1.0f / sqrtf(var + EPSV);
    float ga = gamma[o], be = beta[o];
    float wr[C];
    const float* wp = w + (size_t)o*2*C;
#pragma unroll
    for (int c = 0; c < C; ++c) wr[c] = wp[c];
    float bs = base[(size_t)bq*O + o];
    float m = -3.4e38f;
    for (int k = 0; k < KNN; ++k) {
      float acc = bs;
#pragma unroll
      for (int c = 0; c < C; ++c) acc += wr[c] * ft[k][c];
      float xn = (acc - mu) * rsv;
      float yv = xn*ga + be;
      yv = yv > 0.f ? yv : LEAK*yv;
      m = fmaxf(m, yv);
    }
    fout[(size_t)bq*O + o] = m;
  }
}

extern "C" void kernel_launch(void* const* d_in, const int* in_sizes, int n_in,
                              void* d_out, int out_size, void* d_ws, size_t ws_size,
                              hipStream_t stream) {
  const float* x    = (const float*)d_in[0];
  const float* w_in = (const float*)d_in[3];
  const float* b_in = (const float*)d_in[4];
  const float* w1 = (const float*)d_in[5];
  const float* g1 = (const float*)d_in[6];
  const float* be1= (const float*)d_in[7];
  const float* w2 = (const float*)d_in[8];
  const float* g2 = (const float*)d_in[9];
  const float* be2= (const float*)d_in[10];
  const float* w3 = (const float*)d_in[11];
  const float* g3 = (const float*)d_in[12];
  const float* be3= (const float*)d_in[13];
  const float* w4 = (const float*)d_in[14];
  const float* g4 = (const float*)d_in[15];
  const float* be4= (const float*)d_in[16];
  float* out = (float*)d_out;
  (void)in_sizes; (void)n_in; (void)out_size; (void)ws_size;

  char* ws = (char*)d_ws;
  size_t off = 0;
  auto alloc = [&](size_t count) {
    void* p = ws + off;
    off += (count * 4 + 255) & ~(size_t)255;
    return p;
  };
  float* f0    = (float*)alloc(16*2048*8);
  float* f1    = (float*)alloc(16*2048*32);
  float* f2    = (float*)alloc(16*512*64);
  float* f3    = (float*)alloc(16*512*64);
  float* fq1   = (float*)alloc(16*512*32);
  float* fq2   = (float*)alloc(16*128*64);
  float* cq1   = (float*)alloc(16*512*3);
  float* basep = (float*)alloc(16*2048*32);
  float* stats = (float*)alloc(16*4*2);
  int* idx1    = (int*)alloc(16*2048*16);
  int* idx2    = (int*)alloc(16*512*16);
  int* idx3    = (int*)alloc(16*512*16);
  int* idx4    = (int*)alloc(16*128*16);
  int* fidx1   = (int*)alloc(16*512);
  int* fidx2   = (int*)alloc(16*128);
  float2* part = (float2*)alloc(2 * 16*2048*2*16);  // 8 MB, reused per layer

  float* cq2 = out;              // (16,128,3)
  float* f4  = out + 16*128*3;   // (16,128,128)

  f0_kernel<<<(16*2048)/256, 256, 0, stream>>>(x, w_in, b_in, f0);

  // ---- layer 1: C=8 -> O=32, Nq=2048, keys=x (2048) ----
  knn_part_kernel<<<16*8*2, 256, 0, stream>>>(x, 2048, x, 2048, 2, part);
  knn_merge_kernel<<<(16*2048)/256, 256, 0, stream>>>(part, 2, 16*2048, idx1);
  base_kernel<8,32><<<(16*2048*32)/256, 256, 0, stream>>>(f0, w1, 2048, basep);
  stats_kernel<8,32><<<64, 256, 0, stream>>>(f0, 2048, idx1, 2048, basep, w1, stats);
  final_kernel<8,32><<<16*2048, 64, 0, stream>>>(f0, 2048, idx1, 2048, basep, w1, stats, g1, be1, f1);

  // ---- fps 2048 -> 512 ----
  fps_kernel<8><<<16, 256, 0, stream>>>(x, 512, fidx1);
  gather_kernel<<<(16*512)/256, 256, 0, stream>>>(x, f1, 2048, 32, fidx1, 512, cq1, fq1);

  // ---- layer 2: C=32 -> O=64, Nq=512, keys=x (2048) ----
  knn_part_kernel<<<16*2*8, 256, 0, stream>>>(cq1, 512, x, 2048, 8, part);
  knn_merge_kernel<<<(16*512)/256, 256, 0, stream>>>(part, 8, 16*512, idx2);
  base_kernel<32,64><<<(16*512*64)/256, 256, 0, stream>>>(fq1, w2, 512, basep);
  stats_kernel<32,64><<<64, 256, 0, stream>>>(f1, 2048, idx2, 512, basep, w2, stats);
  final_kernel<32,64><<<16*512, 64, 0, stream>>>(f1, 2048, idx2, 512, basep, w2, stats, g2, be2, f2);

  // ---- layer 3: C=64 -> O=64, Nq=512, keys=cq1 (512) ----
  knn_part_kernel<<<16*2*8, 256, 0, stream>>>(cq1, 512, cq1, 512, 8, part);
  knn_merge_kernel<<<(16*512)/256, 256, 0, stream>>>(part, 8, 16*512, idx3);
  base_kernel<64,64><<<(16*512*64)/256, 256, 0, stream>>>(f2, w3, 512, basep);
  stats_kernel<64,64><<<64, 256, 0, stream>>>(f2, 512, idx3, 512, basep, w3, stats);
  final_kernel<64,64><<<16*512, 64, 0, stream>>>(f2, 512, idx3, 512, basep, w3, stats, g3, be3, f3);

  // ---- fps 512 -> 128 ----
  fps_kernel<2><<<16, 256, 0, stream>>>(cq1, 128, fidx2);
  gather_kernel<<<(16*128)/256, 256, 0, stream>>>(cq1, f3, 512, 64, fidx2, 128, cq2, fq2);

  // ---- layer 4: C=64 -> O=128, Nq=128, keys=cq1 (512) ----
  knn_part_kernel<<<16*1*8, 256, 0, stream>>>(cq2, 128, cq1, 512, 8, part);
  knn_merge_kernel<<<(16*128 + 255)/256, 256, 0, stream>>>(part, 8, 16*128, idx4);
  base_kernel<64,128><<<(16*128*128)/256, 256, 0, stream>>>(fq2, w4, 128, basep);
  stats_kernel<64,128><<<64, 256, 0, stream>>>(f3, 512, idx4, 128, basep, w4, stats);
  final_kernel<64,128><<<16*128, 64, 0, stream>>>(f3, 512, idx4, 128, basep, w4, stats, g4, be4, f4);
}

// Round 4
// 1361.203 us; speedup vs baseline: 2.9593x; 1.1285x over previous
//
#include <hip/hip_runtime.h>

#define KNN 16
static constexpr int BB = 16;
static constexpr float LEAK = 0.2f;
static constexpr float EPSV = 1e-5f;
typedef unsigned long long u64;

// ---------------- f0 = w_in @ coor + b_in  (point-major) ----------------
__global__ __launch_bounds__(256) void f0_kernel(const float* __restrict__ x,
    const float* __restrict__ w_in, const float* __restrict__ b_in,
    float* __restrict__ f0) {
  int i = blockIdx.x * 256 + threadIdx.x;
  if (i >= BB * 2048) return;
  float px = x[i*3+0], py = x[i*3+1], pz = x[i*3+2];
#pragma unroll
  for (int o = 0; o < 8; ++o) {
    f0[i*8+o] = w_in[o*3+0]*px + w_in[o*3+1]*py + w_in[o*3+2]*pz + b_in[o];
  }
}

// ---------------- branch-free bitonic top-16 primitives -------------------
__device__ __forceinline__ void ce_asc(u64 &a, u64 &b) {
  u64 x = a, y = b; bool sw = y < x; a = sw ? y : x; b = sw ? x : y;
}
__device__ __forceinline__ void ce_desc(u64 &a, u64 &b) {
  u64 x = a, y = b; bool sw = x < y; a = sw ? y : x; b = sw ? x : y;
}
__device__ __forceinline__ void bitonic_sort16(u64 *T) {
#pragma unroll
  for (int k = 2; k <= 16; k <<= 1) {
#pragma unroll
    for (int j = k >> 1; j > 0; j >>= 1) {
#pragma unroll
      for (int i = 0; i < 16; ++i) {
        int l = i ^ j;
        if (l > i) {
          if ((i & k) == 0) ce_asc(T[i], T[l]); else ce_desc(T[i], T[l]);
        }
      }
    }
  }
}
// R asc, T asc -> R = 16 smallest of union, sorted asc
__device__ __forceinline__ void merge_sorted16(u64 *R, const u64 *T) {
#pragma unroll
  for (int i = 0; i < 16; ++i) {
    u64 t = T[15 - i];
    R[i] = t < R[i] ? t : R[i];
  }
#pragma unroll
  for (int j = 8; j > 0; j >>= 1) {
#pragma unroll
    for (int i = 0; i < 16; ++i) {
      int l = i ^ j;
      if (l > i) ce_asc(R[i], R[l]);
    }
  }
}

// ---------------- kNN split-K: per-(qchunk,kchunk) partial top-16 ----------
// part[((b*Nq+q)*KC + c)*16 + s] = u64 key (sorted ascending within chunk)
// key = (order-monotone dist bits << 32) | key_index
__global__ __launch_bounds__(256) void knn_part_kernel(
    const float* __restrict__ qxyz, int Nq,
    const float* __restrict__ kxyz, int Nk,
    int KC, u64* __restrict__ part) {
  __shared__ float4 keys[1024];
  int nqb = (Nq + 255) >> 8;
  int bid = blockIdx.x;
  int c  = bid % KC;
  int qb = (bid / KC) % nqb;
  int b  = bid / (KC * nqb);
  int nkc = Nk / KC;              // keys per chunk (<=1024, multiple of 16)
  int kbase = c * nkc;
  for (int j = threadIdx.x; j < nkc; j += 256) {
    const float* kp = kxyz + (size_t)(b*Nk + kbase + j)*3;
    float kx = kp[0], ky = kp[1], kz = kp[2];
    keys[j] = make_float4(kx, ky, kz, kx*kx + ky*ky + kz*kz);
  }
  __syncthreads();
  int q = (qb << 8) + threadIdx.x;
  if (q >= Nq) return;
  const float* qp = qxyz + (size_t)(b*Nq + q)*3;
  float qx = qp[0], qy = qp[1], qz = qp[2];
  float q2 = qx*qx + qy*qy + qz*qz;
  u64 R[16];
#pragma unroll
  for (int s = 0; s < 16; ++s) R[s] = 0xFFFFFFFFFFFFFFFFull;
  for (int j0 = 0; j0 < nkc; j0 += 16) {
    u64 T[16];
#pragma unroll
    for (int u = 0; u < 16; ++u) {
      float4 kk = keys[j0 + u];
      float qk = qx*kk.x + qy*kk.y + qz*kk.z;
      float d2 = q2 + kk.w - 2.0f*qk;
      int bb = __float_as_int(d2);
      unsigned k32 = (unsigned)bb ^ (unsigned)((bb >> 31) | 0x80000000);
      T[u] = ((u64)k32 << 32) | (unsigned)(kbase + j0 + u);
    }
    bitonic_sort16(T);
    merge_sorted16(R, T);
  }
  u64* op = part + ((size_t)(b*Nq + q)*KC + c)*KNN;
#pragma unroll
  for (int s = 0; s < KNN; ++s) op[s] = R[s];
}

// ---------------- merge KC sorted-16 lists -> final top-16 indices --------
__global__ __launch_bounds__(256) void knn_merge_kernel(
    const u64* __restrict__ part, int KC, int total, int* __restrict__ idx) {
  int i = blockIdx.x * 256 + threadIdx.x;
  if (i >= total) return;
  const u64* p = part + (size_t)i * KC * KNN;
  u64 R[16];
#pragma unroll
  for (int s = 0; s < 16; ++s) R[s] = p[s];
  for (int c = 1; c < KC; ++c) {
    u64 T[16];
#pragma unroll
    for (int s = 0; s < 16; ++s) T[s] = p[(size_t)c*KNN + s];
    merge_sorted16(R, T);
  }
  int* op = idx + (size_t)i * KNN;
#pragma unroll
  for (int s = 0; s < KNN; ++s) op[s] = (int)(unsigned)(R[s] & 0xFFFFFFFFu);
}

// ---------------- FPS: packed-u64 argmax, DPP wave reduce -----------------
// key = (float_bits(dist) << 32) | ~idx : u64 max == (max dist, min idx).
// (dist here is a sum of squares, always >= 0, so raw float bits are monotone)
__device__ __forceinline__ u64 fps_max64(u64 a, u64 b) { return a > b ? a : b; }
template<int CTRL>
__device__ __forceinline__ u64 fps_dpp_u64(u64 v) {
  unsigned lo = (unsigned)__builtin_amdgcn_update_dpp(0, (int)(unsigned)(v & 0xFFFFFFFFull),
                                                      CTRL, 0xF, 0xF, false);
  unsigned hi = (unsigned)__builtin_amdgcn_update_dpp(0, (int)(unsigned)(v >> 32),
                                                      CTRL, 0xF, 0xF, false);
  return ((u64)hi << 32) | lo;
}
template<int P>
__global__ __launch_bounds__(256) void fps_kernel(const float* __restrict__ xyz,
    int np, int* __restrict__ fidx) {
  constexpr int NN = P * 256;
  __shared__ float sx[NN], sy[NN], sz[NN];
  __shared__ u64 s_key[2][4];
  int b = blockIdx.x;
  int tid = threadIdx.x;
  float px[P], py[P], pz[P], dl[P];
#pragma unroll
  for (int i = 0; i < P; ++i) {
    int p = tid + (i << 8);
    const float* pp = xyz + (size_t)(b*NN + p)*3;
    px[i] = pp[0]; py[i] = pp[1]; pz[i] = pp[2];
    sx[p] = px[i]; sy[p] = py[i]; sz[p] = pz[i];
    dl[i] = 1e10f;
  }
  __syncthreads();
  int far = 0;
  for (int t = 0; t < np; ++t) {
    if (tid == 0) fidx[b*np + t] = far;
    float cx = sx[far], cy = sy[far], cz = sz[far];  // uniform LDS broadcast
    float bv = -1.0f; int bi = 0;
#pragma unroll
    for (int i = 0; i < P; ++i) {
      float dx = __fsub_rn(px[i], cx);
      float dy = __fsub_rn(py[i], cy);
      float dz = __fsub_rn(pz[i], cz);
      float d = __fadd_rn(__fadd_rn(__fmul_rn(dx,dx), __fmul_rn(dy,dy)), __fmul_rn(dz,dz));
      dl[i] = fminf(dl[i], d);
      if (dl[i] > bv) { bv = dl[i]; bi = tid + (i << 8); }  // ascending i => min idx on ties
    }
    u64 k = ((u64)__float_as_uint(bv) << 32) | (unsigned)(~bi);
    k = fps_max64(k, fps_dpp_u64<0x111>(k));  // row_shr:1
    k = fps_max64(k, fps_dpp_u64<0x112>(k));  // row_shr:2
    k = fps_max64(k, fps_dpp_u64<0x114>(k));  // row_shr:4
    k = fps_max64(k, fps_dpp_u64<0x118>(k));  // row_shr:8
    k = fps_max64(k, fps_dpp_u64<0x142>(k));  // row_bcast:15
    k = fps_max64(k, fps_dpp_u64<0x143>(k));  // row_bcast:31
    unsigned wlo = (unsigned)__builtin_amdgcn_readlane((int)(unsigned)(k & 0xFFFFFFFFull), 63);
    unsigned whi = (unsigned)__builtin_amdgcn_readlane((int)(unsigned)(k >> 32), 63);
    int buf = t & 1;
    if ((tid & 63) == 0)
      s_key[buf][tid >> 6] = ((u64)whi << 32) | wlo;
    __syncthreads();
    u64 best = s_key[buf][0];
    best = fps_max64(best, s_key[buf][1]);
    best = fps_max64(best, s_key[buf][2]);
    best = fps_max64(best, s_key[buf][3]);
    far = (int)(~(unsigned)(best & 0xFFFFFFFFull));  // uniform across block
  }
}

// ---------------- gather coor_q / f_q by FPS indices ----------------------
__global__ __launch_bounds__(256) void gather_kernel(const float* __restrict__ coor,
    const float* __restrict__ f, int Nsrc, int C, const int* __restrict__ fidx,
    int np, float* __restrict__ coor_q, float* __restrict__ f_q) {
  int i = blockIdx.x * 256 + threadIdx.x;
  if (i >= BB * np) return;
  int b = i / np;
  int src = fidx[i];
  const float* cs = coor + (size_t)(b*Nsrc + src)*3;
  coor_q[i*3+0] = cs[0]; coor_q[i*3+1] = cs[1]; coor_q[i*3+2] = cs[2];
  const float* fs = f + (size_t)(b*Nsrc + src)*C;
  float* fd = f_q + (size_t)i*C;
  for (int c = 0; c < C; ++c) fd[c] = fs[c];
}

// ---------------- base[b,q,o] = sum_c (w[o,C+c]-w[o,c]) * xq[c] -----------
template<int C, int O>
__global__ __launch_bounds__(256) void base_kernel(const float* __restrict__ fq,
    const float* __restrict__ w, int Nq, float* __restrict__ base) {
  int i = blockIdx.x * 256 + threadIdx.x;
  if (i >= BB * Nq * O) return;
  int o = i % O;
  int bq = i / O;
  const float* fr = fq + (size_t)bq * C;
  const float* wr = w + (size_t)o * 2 * C;
  float acc = 0.f;
#pragma unroll
  for (int c = 0; c < C; ++c) acc += (wr[C + c] - wr[c]) * fr[c];
  base[i] = acc;
}

// ---------------- group-norm stats: one block per (b, group) --------------
template<int C, int O>
__global__ __launch_bounds__(256) void stats_kernel(const float* __restrict__ fsrc, int Nsrc,
    const int* __restrict__ idx, int Nq, const float* __restrict__ base,
    const float* __restrict__ w, float* __restrict__ stats) {
  constexpr int Og = O / 4;
  __shared__ float wl[Og * C];
  __shared__ double rs[256], rs2[256];
  int b = blockIdx.x >> 2;
  int g = blockIdx.x & 3;
  for (int t = threadIdx.x; t < Og * C; t += 256) {
    int o = g*Og + t / C; int c = t % C;
    wl[t] = w[(size_t)o*2*C + c];
  }
  __syncthreads();
  double s = 0.0, s2 = 0.0;
  int total = Nq * KNN;
  for (int e = threadIdx.x; e < total; e += 256) {
    int q = e >> 4, k = e & 15;
    int src = idx[(size_t)(b*Nq + q)*KNN + k];
    const float* fr = fsrc + (size_t)(b*Nsrc + src)*C;
    float ft[C];
#pragma unroll
    for (int c = 0; c < C; ++c) ft[c] = fr[c];
    const float* bp = base + (size_t)(b*Nq + q)*O + g*Og;
    for (int oo = 0; oo < Og; ++oo) {
      float acc = bp[oo];
      const float* wo = &wl[oo*C];
#pragma unroll
      for (int c = 0; c < C; ++c) acc += wo[c] * ft[c];
      s += acc;
      s2 += (double)acc * (double)acc;
    }
  }
  rs[threadIdx.x] = s; rs2[threadIdx.x] = s2;
  __syncthreads();
  for (int off = 128; off > 0; off >>= 1) {
    if (threadIdx.x < off) {
      rs[threadIdx.x] += rs[threadIdx.x+off];
      rs2[threadIdx.x] += rs2[threadIdx.x+off];
    }
    __syncthreads();
  }
  if (threadIdx.x == 0) {
    double cnt = (double)Og * (double)Nq * (double)KNN;
    double mu = rs[0] / cnt;
    double var = rs2[0] / cnt - mu*mu;
    stats[blockIdx.x*2 + 0] = (float)mu;
    stats[blockIdx.x*2 + 1] = (float)var;
  }
}

// ---------------- finalize: y -> GN -> lrelu -> max over k ----------------
template<int C, int O>
__global__ __launch_bounds__(64) void final_kernel(const float* __restrict__ fsrc, int Nsrc,
    const int* __restrict__ idx, int Nq, const float* __restrict__ base,
    const float* __restrict__ w, const float* __restrict__ stats,
    const float* __restrict__ gamma, const float* __restrict__ beta,
    float* __restrict__ fout) {
  constexpr int Og = O / 4;
  __shared__ float ft[KNN][C];
  int bq = blockIdx.x;
  int b = bq / Nq;
  const int* ip = idx + (size_t)bq * KNN;
  for (int t = threadIdx.x; t < KNN * C; t += 64) {
    int k = t / C, c = t % C;
    ft[k][c] = fsrc[(size_t)(b*Nsrc + ip[k])*C + c];
  }
  __syncthreads();
  for (int o = threadIdx.x; o < O; o += 64) {
    int g = o / Og;
    float mu  = stats[(b*4+g)*2 + 0];
    float var = stats[(b*4+g)*2 + 1];
    float rsv = 1.0f / sqrtf(var + EPSV);
    float ga = gamma[o], be = beta[o];
    float wr[C];
    const float* wp = w + (size_t)o*2*C;
#pragma unroll
    for (int c = 0; c < C; ++c) wr[c] = wp[c];
    float bs = base[(size_t)bq*O + o];
    float m = -3.4e38f;
    for (int k = 0; k < KNN; ++k) {
      float acc = bs;
#pragma unroll
      for (int c = 0; c < C; ++c) acc += wr[c] * ft[k][c];
      float xn = (acc - mu) * rsv;
      float yv = xn*ga + be;
      yv = yv > 0.f ? yv : LEAK*yv;
      m = fmaxf(m, yv);
    }
    fout[(size_t)bq*O + o] = m;
  }
}

extern "C" void kernel_launch(void* const* d_in, const int* in_sizes, int n_in,
                              void* d_out, int out_size, void* d_ws, size_t ws_size,
                              hipStream_t stream) {
  const float* x    = (const float*)d_in[0];
  const float* w_in = (const float*)d_in[3];
  const float* b_in = (const float*)d_in[4];
  const float* w1 = (const float*)d_in[5];
  const float* g1 = (const float*)d_in[6];
  const float* be1= (const float*)d_in[7];
  const float* w2 = (const float*)d_in[8];
  const float* g2 = (const float*)d_in[9];
  const float* be2= (const float*)d_in[10];
  const float* w3 = (const float*)d_in[11];
  const float* g3 = (const float*)d_in[12];
  const float* be3= (const float*)d_in[13];
  const float* w4 = (const float*)d_in[14];
  const float* g4 = (const float*)d_in[15];
  const float* be4= (const float*)d_in[16];
  float* out = (float*)d_out;
  (void)in_sizes; (void)n_in; (void)out_size; (void)ws_size;

  char* ws = (char*)d_ws;
  size_t off = 0;
  auto alloc = [&](size_t count) {
    void* p = ws + off;
    off += (count * 4 + 255) & ~(size_t)255;
    return p;
  };
  float* f0    = (float*)alloc(16*2048*8);
  float* f1    = (float*)alloc(16*2048*32);
  float* f2    = (float*)alloc(16*512*64);
  float* f3    = (float*)alloc(16*512*64);
  float* fq1   = (float*)alloc(16*512*32);
  float* fq2   = (float*)alloc(16*128*64);
  float* cq1   = (float*)alloc(16*512*3);
  float* basep = (float*)alloc(16*2048*32);
  float* stats = (float*)alloc(16*4*2);
  int* idx1    = (int*)alloc(16*2048*16);
  int* idx2    = (int*)alloc(16*512*16);
  int* idx3    = (int*)alloc(16*512*16);
  int* idx4    = (int*)alloc(16*128*16);
  int* fidx1   = (int*)alloc(16*512);
  int* fidx2   = (int*)alloc(16*128);
  u64* part    = (u64*)alloc(2 * 16*2048*2*16);  // 8 MB, reused per layer

  float* cq2 = out;              // (16,128,3)
  float* f4  = out + 16*128*3;   // (16,128,128)

  f0_kernel<<<(16*2048)/256, 256, 0, stream>>>(x, w_in, b_in, f0);

  // ---- layer 1: C=8 -> O=32, Nq=2048, keys=x (2048) ----
  knn_part_kernel<<<16*8*2, 256, 0, stream>>>(x, 2048, x, 2048, 2, part);
  knn_merge_kernel<<<(16*2048)/256, 256, 0, stream>>>(part, 2, 16*2048, idx1);
  base_kernel<8,32><<<(16*2048*32)/256, 256, 0, stream>>>(f0, w1, 2048, basep);
  stats_kernel<8,32><<<64, 256, 0, stream>>>(f0, 2048, idx1, 2048, basep, w1, stats);
  final_kernel<8,32><<<16*2048, 64, 0, stream>>>(f0, 2048, idx1, 2048, basep, w1, stats, g1, be1, f1);

  // ---- fps 2048 -> 512 ----
  fps_kernel<8><<<16, 256, 0, stream>>>(x, 512, fidx1);
  gather_kernel<<<(16*512)/256, 256, 0, stream>>>(x, f1, 2048, 32, fidx1, 512, cq1, fq1);

  // ---- layer 2: C=32 -> O=64, Nq=512, keys=x (2048) ----
  knn_part_kernel<<<16*2*8, 256, 0, stream>>>(cq1, 512, x, 2048, 8, part);
  knn_merge_kernel<<<(16*512)/256, 256, 0, stream>>>(part, 8, 16*512, idx2);
  base_kernel<32,64><<<(16*512*64)/256, 256, 0, stream>>>(fq1, w2, 512, basep);
  stats_kernel<32,64><<<64, 256, 0, stream>>>(f1, 2048, idx2, 512, basep, w2, stats);
  final_kernel<32,64><<<16*512, 64, 0, stream>>>(f1, 2048, idx2, 512, basep, w2, stats, g2, be2, f2);

  // ---- layer 3: C=64 -> O=64, Nq=512, keys=cq1 (512) ----
  knn_part_kernel<<<16*2*8, 256, 0, stream>>>(cq1, 512, cq1, 512, 8, part);
  knn_merge_kernel<<<(16*512)/256, 256, 0, stream>>>(part, 8, 16*512, idx3);
  base_kernel<64,64><<<(16*512*64)/256, 256, 0, stream>>>(f2, w3, 512, basep);
  stats_kernel<64,64><<<64, 256, 0, stream>>>(f2, 512, idx3, 512, basep, w3, stats);
  final_kernel<64,64><<<16*512, 64, 0, stream>>>(f2, 512, idx3, 512, basep, w3, stats, g3, be3, f3);

  // ---- fps 512 -> 128 ----
  fps_kernel<2><<<16, 256, 0, stream>>>(cq1, 128, fidx2);
  gather_kernel<<<(16*128)/256, 256, 0, stream>>>(cq1, f3, 512, 64, fidx2, 128, cq2, fq2);

  // ---- layer 4: C=64 -> O=128, Nq=128, keys=cq1 (512) ----
  knn_part_kernel<<<16*1*8, 256, 0, stream>>>(cq2, 128, cq1, 512, 8, part);
  knn_merge_kernel<<<(16*128 + 255)/256, 256, 0, stream>>>(part, 8, 16*128, idx4);
  base_kernel<64,128><<<(16*128*128)/256, 256, 0, stream>>>(fq2, w4, 128, basep);
  stats_kernel<64,128><<<64, 256, 0, stream>>>(f3, 512, idx4, 128, basep, w4, stats);
  final_kernel<64,128><<<16*128, 64, 0, stream>>>(f3, 512, idx4, 128, basep, w4, stats, g4, be4, f4);
}

// Round 5
// 707.326 us; speedup vs baseline: 5.6950x; 1.9244x over previous
//
#include <hip/hip_runtime.h>

#define KNN 16
static constexpr int BB = 16;
static constexpr float LEAK = 0.2f;
static constexpr float EPSV = 1e-5f;
typedef unsigned long long u64;

// ---------------- branch-free bitonic top-16 primitives -------------------
__device__ __forceinline__ void ce_asc(u64 &a, u64 &b) {
  u64 x = a, y = b; bool sw = y < x; a = sw ? y : x; b = sw ? x : y;
}
__device__ __forceinline__ void ce_desc(u64 &a, u64 &b) {
  u64 x = a, y = b; bool sw = x < y; a = sw ? y : x; b = sw ? x : y;
}
__device__ __forceinline__ void bitonic_sort16(u64 *T) {
#pragma unroll
  for (int k = 2; k <= 16; k <<= 1) {
#pragma unroll
    for (int j = k >> 1; j > 0; j >>= 1) {
#pragma unroll
      for (int i = 0; i < 16; ++i) {
        int l = i ^ j;
        if (l > i) {
          if ((i & k) == 0) ce_asc(T[i], T[l]); else ce_desc(T[i], T[l]);
        }
      }
    }
  }
}
// R asc, T asc -> R = 16 smallest of union, sorted asc
__device__ __forceinline__ void merge_sorted16(u64 *R, const u64 *T) {
#pragma unroll
  for (int i = 0; i < 16; ++i) {
    u64 t = T[15 - i];
    R[i] = t < R[i] ? t : R[i];
  }
#pragma unroll
  for (int j = 8; j > 0; j >>= 1) {
#pragma unroll
    for (int i = 0; i < 16; ++i) {
      int l = i ^ j;
      if (l > i) ce_asc(R[i], R[l]);
    }
  }
}

// ---------------- device: f0 = w_in @ coor + b_in -------------------------
__device__ __forceinline__ void f0_dev(const float* __restrict__ x,
    const float* __restrict__ w_in, const float* __restrict__ b_in,
    float* __restrict__ f0, int bid) {
  int i = bid * 256 + threadIdx.x;
  float px = x[i*3+0], py = x[i*3+1], pz = x[i*3+2];
#pragma unroll
  for (int o = 0; o < 8; ++o) {
    f0[i*8+o] = w_in[o*3+0]*px + w_in[o*3+1]*py + w_in[o*3+2]*pz + b_in[o];
  }
}

// ---------------- device: kNN split-K partial top-16 ----------------------
__device__ void knn_part_dev(const float* __restrict__ qxyz, int Nq,
    const float* __restrict__ kxyz, int Nk, int KC, u64* __restrict__ part,
    int bid) {
  __shared__ float4 keys[1024];
  int nqb = (Nq + 255) >> 8;
  int c  = bid % KC;
  int qb = (bid / KC) % nqb;
  int b  = bid / (KC * nqb);
  int nkc = Nk / KC;
  int kbase = c * nkc;
  for (int j = threadIdx.x; j < nkc; j += 256) {
    const float* kp = kxyz + (size_t)(b*Nk + kbase + j)*3;
    float kx = kp[0], ky = kp[1], kz = kp[2];
    keys[j] = make_float4(kx, ky, kz, kx*kx + ky*ky + kz*kz);
  }
  __syncthreads();
  int q = (qb << 8) + threadIdx.x;
  if (q >= Nq) return;
  const float* qp = qxyz + (size_t)(b*Nq + q)*3;
  float qx = qp[0], qy = qp[1], qz = qp[2];
  float q2 = qx*qx + qy*qy + qz*qz;
  u64 R[16];
#pragma unroll
  for (int s = 0; s < 16; ++s) R[s] = 0xFFFFFFFFFFFFFFFFull;
  for (int j0 = 0; j0 < nkc; j0 += 16) {
    u64 T[16];
#pragma unroll
    for (int u = 0; u < 16; ++u) {
      float4 kk = keys[j0 + u];
      float qk = qx*kk.x + qy*kk.y + qz*kk.z;
      float d2 = q2 + kk.w - 2.0f*qk;
      int bb = __float_as_int(d2);
      unsigned k32 = (unsigned)bb ^ (unsigned)((bb >> 31) | 0x80000000);
      T[u] = ((u64)k32 << 32) | (unsigned)(kbase + j0 + u);
    }
    bitonic_sort16(T);
    merge_sorted16(R, T);
  }
  u64* op = part + ((size_t)(b*Nq + q)*KC + c)*KNN;
#pragma unroll
  for (int s = 0; s < KNN; ++s) op[s] = R[s];
}

// ---------------- device: merge KC sorted-16 lists -> idx -----------------
__device__ __forceinline__ void merge_dev(const u64* __restrict__ part, int KC,
    int total, int* __restrict__ idx, int bid) {
  int i = bid * 256 + threadIdx.x;
  if (i >= total) return;
  const u64* p = part + (size_t)i * KC * KNN;
  u64 R[16];
#pragma unroll
  for (int s = 0; s < 16; ++s) R[s] = p[s];
  for (int c = 1; c < KC; ++c) {
    u64 T[16];
#pragma unroll
    for (int s = 0; s < 16; ++s) T[s] = p[(size_t)c*KNN + s];
    merge_sorted16(R, T);
  }
  int* op = idx + (size_t)i * KNN;
#pragma unroll
  for (int s = 0; s < KNN; ++s) op[s] = (int)(unsigned)(R[s] & 0xFFFFFFFFu);
}

// ---------------- device: base[b,q,o] = sum_c (w[o,C+c]-w[o,c])*fq[c] -----
template<int C, int O>
__device__ __forceinline__ void base_dev(const float* __restrict__ fq,
    const float* __restrict__ w, int Nq, float* __restrict__ base, int bid) {
  int i = bid * 256 + threadIdx.x;
  if (i >= BB * Nq * O) return;
  int o = i % O;
  int bq = i / O;
  const float* fr = fq + (size_t)bq * C;
  const float* wr = w + (size_t)o * 2 * C;
  float acc = 0.f;
#pragma unroll
  for (int c = 0; c < C; ++c) acc += (wr[C + c] - wr[c]) * fr[c];
  base[i] = acc;
}

// ---------------- device: FPS (packed-u64 DPP argmax) ---------------------
__device__ __forceinline__ u64 fps_max64(u64 a, u64 b) { return a > b ? a : b; }
template<int CTRL>
__device__ __forceinline__ u64 fps_dpp_u64(u64 v) {
  unsigned lo = (unsigned)__builtin_amdgcn_update_dpp(0, (int)(unsigned)(v & 0xFFFFFFFFull),
                                                      CTRL, 0xF, 0xF, false);
  unsigned hi = (unsigned)__builtin_amdgcn_update_dpp(0, (int)(unsigned)(v >> 32),
                                                      CTRL, 0xF, 0xF, false);
  return ((u64)hi << 32) | lo;
}
template<int P>
__device__ void fps_dev(const float* __restrict__ xyz, int np,
    int* __restrict__ fidx, int b) {
  constexpr int NN = P * 256;
  __shared__ float sx[NN], sy[NN], sz[NN];
  __shared__ u64 s_key[2][4];
  int tid = threadIdx.x;
  float px[P], py[P], pz[P], dl[P];
#pragma unroll
  for (int i = 0; i < P; ++i) {
    int p = tid + (i << 8);
    const float* pp = xyz + (size_t)(b*NN + p)*3;
    px[i] = pp[0]; py[i] = pp[1]; pz[i] = pp[2];
    sx[p] = px[i]; sy[p] = py[i]; sz[p] = pz[i];
    dl[i] = 1e10f;
  }
  __syncthreads();
  int far = 0;
  for (int t = 0; t < np; ++t) {
    if (tid == 0) fidx[b*np + t] = far;
    float cx = sx[far], cy = sy[far], cz = sz[far];
    float bv = -1.0f; int bi = 0;
#pragma unroll
    for (int i = 0; i < P; ++i) {
      float dx = __fsub_rn(px[i], cx);
      float dy = __fsub_rn(py[i], cy);
      float dz = __fsub_rn(pz[i], cz);
      float d = __fadd_rn(__fadd_rn(__fmul_rn(dx,dx), __fmul_rn(dy,dy)), __fmul_rn(dz,dz));
      dl[i] = fminf(dl[i], d);
      if (dl[i] > bv) { bv = dl[i]; bi = tid + (i << 8); }
    }
    u64 k = ((u64)__float_as_uint(bv) << 32) | (unsigned)(~bi);
    k = fps_max64(k, fps_dpp_u64<0x111>(k));
    k = fps_max64(k, fps_dpp_u64<0x112>(k));
    k = fps_max64(k, fps_dpp_u64<0x114>(k));
    k = fps_max64(k, fps_dpp_u64<0x118>(k));
    k = fps_max64(k, fps_dpp_u64<0x142>(k));
    k = fps_max64(k, fps_dpp_u64<0x143>(k));
    unsigned wlo = (unsigned)__builtin_amdgcn_readlane((int)(unsigned)(k & 0xFFFFFFFFull), 63);
    unsigned whi = (unsigned)__builtin_amdgcn_readlane((int)(unsigned)(k >> 32), 63);
    int buf = t & 1;
    if ((tid & 63) == 0)
      s_key[buf][tid >> 6] = ((u64)whi << 32) | wlo;
    __syncthreads();
    u64 best = s_key[buf][0];
    best = fps_max64(best, s_key[buf][1]);
    best = fps_max64(best, s_key[buf][2]);
    best = fps_max64(best, s_key[buf][3]);
    far = (int)(~(unsigned)(best & 0xFFFFFFFFull));
  }
}

// ---------------- fused dispatches ----------------------------------------
__global__ __launch_bounds__(256) void fusedA_kernel(const float* __restrict__ x,
    const float* __restrict__ w_in, const float* __restrict__ b_in,
    float* __restrict__ f0, u64* __restrict__ part, int* __restrict__ fidx1) {
  int bid = blockIdx.x;
  if (bid < 256)      knn_part_dev(x, 2048, x, 2048, 2, part, bid);
  else if (bid < 384) f0_dev(x, w_in, b_in, f0, bid - 256);
  else                fps_dev<8>(x, 512, fidx1, bid - 384);
}

__global__ __launch_bounds__(256) void fusedB_kernel(const float* __restrict__ cq1,
    const float* __restrict__ x, u64* __restrict__ part2, u64* __restrict__ part3,
    int* __restrict__ fidx2) {
  int bid = blockIdx.x;
  if (bid < 128)      knn_part_dev(cq1, 512, x, 2048, 4, part2, bid);
  else if (bid < 256) knn_part_dev(cq1, 512, cq1, 512, 4, part3, bid - 128);
  else                fps_dev<2>(cq1, 128, fidx2, bid - 256);
}

__global__ __launch_bounds__(256) void fusedC1_kernel(const u64* __restrict__ part,
    int* __restrict__ idx1, const float* __restrict__ f0,
    const float* __restrict__ w1, float* __restrict__ basep) {
  int bid = blockIdx.x;
  if (bid < 128) merge_dev(part, 2, 16*2048, idx1, bid);
  else           base_dev<8,32>(f0, w1, 2048, basep, bid - 128);
}

__global__ __launch_bounds__(256) void fusedC2_kernel(const u64* __restrict__ part2,
    int* __restrict__ idx2, const u64* __restrict__ part3, int* __restrict__ idx3,
    const float* __restrict__ fq1, const float* __restrict__ w2,
    float* __restrict__ basep) {
  int bid = blockIdx.x;
  if (bid < 32)      merge_dev(part2, 4, 16*512, idx2, bid);
  else if (bid < 64) merge_dev(part3, 4, 16*512, idx3, bid - 32);
  else               base_dev<32,64>(fq1, w2, 512, basep, bid - 64);
}

__global__ __launch_bounds__(256) void fusedD_kernel(const float* __restrict__ cq2,
    const float* __restrict__ cq1, u64* __restrict__ part,
    const float* __restrict__ fq2, const float* __restrict__ w4,
    float* __restrict__ basep) {
  int bid = blockIdx.x;
  if (bid < 128) knn_part_dev(cq2, 128, cq1, 512, 8, part, bid);
  else           base_dev<64,128>(fq2, w4, 128, basep, bid - 128);
}

__global__ __launch_bounds__(256) void merge_kernel(const u64* __restrict__ part,
    int KC, int total, int* __restrict__ idx) {
  merge_dev(part, KC, total, idx, blockIdx.x);
}

__global__ __launch_bounds__(256) void base3_kernel(const float* __restrict__ f2,
    const float* __restrict__ w3, float* __restrict__ basep) {
  base_dev<64,64>(f2, w3, 512, basep, blockIdx.x);
}

// ---------------- gather coor_q / f_q by FPS indices ----------------------
__global__ __launch_bounds__(256) void gather_kernel(const float* __restrict__ coor,
    const float* __restrict__ f, int Nsrc, int C, const int* __restrict__ fidx,
    int np, float* __restrict__ coor_q, float* __restrict__ f_q) {
  int i = blockIdx.x * 256 + threadIdx.x;
  if (i >= BB * np) return;
  int b = i / np;
  int src = fidx[i];
  const float* cs = coor + (size_t)(b*Nsrc + src)*3;
  coor_q[i*3+0] = cs[0]; coor_q[i*3+1] = cs[1]; coor_q[i*3+2] = cs[2];
  const float* fs = f + (size_t)(b*Nsrc + src)*C;
  float* fd = f_q + (size_t)i*C;
  for (int c = 0; c < C; ++c) fd[c] = fs[c];
}

// ---------------- group-norm partial stats: grid = B*4*8 ------------------
template<int C, int O>
__global__ __launch_bounds__(256) void stats_part_kernel(const float* __restrict__ fsrc,
    int Nsrc, const int* __restrict__ idx, int Nq, const float* __restrict__ base,
    const float* __restrict__ w, double2* __restrict__ pp) {
  constexpr int Og = O / 4;
  __shared__ float wl[Og * C];
  __shared__ double rs[256], rs2[256];
  int bg = blockIdx.x >> 3;
  int chunk = blockIdx.x & 7;
  int b = bg >> 2, g = bg & 3;
  for (int t = threadIdx.x; t < Og * C; t += 256) {
    int o = g*Og + t / C; int c = t % C;
    wl[t] = w[(size_t)o*2*C + c];
  }
  __syncthreads();
  double s = 0.0, s2 = 0.0;
  int csz = (Nq * KNN) >> 3;
  int e_end = (chunk + 1) * csz;
  for (int e = chunk*csz + threadIdx.x; e < e_end; e += 256) {
    int q = e >> 4, k = e & 15;
    int src = idx[(size_t)(b*Nq + q)*KNN + k];
    const float4* fr4 = (const float4*)(fsrc + (size_t)(b*Nsrc + src)*C);
    float ft[C];
#pragma unroll
    for (int c4 = 0; c4 < C/4; ++c4) {
      float4 v = fr4[c4];
      ft[c4*4+0] = v.x; ft[c4*4+1] = v.y; ft[c4*4+2] = v.z; ft[c4*4+3] = v.w;
    }
    const float* bp = base + (size_t)(b*Nq + q)*O + g*Og;
    for (int oo = 0; oo < Og; ++oo) {
      float acc = bp[oo];
      const float* wo = &wl[oo*C];
#pragma unroll
      for (int c = 0; c < C; ++c) acc += wo[c] * ft[c];
      s += acc;
      s2 += (double)acc * (double)acc;
    }
  }
  rs[threadIdx.x] = s; rs2[threadIdx.x] = s2;
  __syncthreads();
  for (int off = 128; off > 0; off >>= 1) {
    if (threadIdx.x < off) {
      rs[threadIdx.x] += rs[threadIdx.x+off];
      rs2[threadIdx.x] += rs2[threadIdx.x+off];
    }
    __syncthreads();
  }
  if (threadIdx.x == 0) pp[blockIdx.x] = make_double2(rs[0], rs2[0]);
}

// ---------------- finalize: reduce partials, conv+GN+lrelu+max ------------
template<int C, int O, int QB>
__global__ __launch_bounds__(256) void fin_kernel(const float* __restrict__ fsrc,
    int Nsrc, const int* __restrict__ idx, int Nq, const float* __restrict__ base,
    const float* __restrict__ w, const double2* __restrict__ pp,
    const float* __restrict__ gamma, const float* __restrict__ beta,
    float* __restrict__ fout) {
  constexpr int Og = O / 4;
  constexpr int C4 = C / 4;
  __shared__ float ft[QB][KNN][C];
  __shared__ float s_mu[4], s_rsv[4];
  int tid = threadIdx.x;
  int nb = Nq / QB;
  int b = blockIdx.x / nb;
  int q0 = (blockIdx.x % nb) * QB;
  constexpr int V = QB * KNN * C4;
  for (int v = tid; v < V; v += 256) {
    int row = v / C4, w4 = v % C4;
    int ql = row / KNN, k = row % KNN;
    int src = idx[(size_t)(b*Nq + q0 + ql)*KNN + k];
    ((float4*)&ft[ql][k][0])[w4] = ((const float4*)(fsrc + (size_t)(b*Nsrc + src)*C))[w4];
  }
  if (tid < 4) {
    double s = 0.0, s2 = 0.0;
#pragma unroll
    for (int c2 = 0; c2 < 8; ++c2) {
      double2 p = pp[(b*4 + tid)*8 + c2];
      s += p.x; s2 += p.y;
    }
    double cnt = (double)Og * (double)Nq * (double)KNN;
    double mu = s / cnt;
    double var = s2 / cnt - mu*mu;
    s_mu[tid] = (float)mu;
    s_rsv[tid] = 1.0f / sqrtf((float)var + EPSV);
  }
  __syncthreads();
  int ql = tid / O, o = tid % O;
  int g = o / Og;
  float mu = s_mu[g], rsv = s_rsv[g];
  float ga = gamma[o], be = beta[o];
  float4 wr4[C4];
  const float4* wp4 = (const float4*)(w + (size_t)o*2*C);
#pragma unroll
  for (int c4 = 0; c4 < C4; ++c4) wr4[c4] = wp4[c4];
  float bs = base[(size_t)(b*Nq + q0 + ql)*O + o];
  float m = -3.4e38f;
  for (int k = 0; k < KNN; ++k) {
    float acc = bs;
    const float4* fv = (const float4*)&ft[ql][k][0];
#pragma unroll
    for (int c4 = 0; c4 < C4; ++c4) {
      float4 v = fv[c4];
      acc += wr4[c4].x*v.x; acc += wr4[c4].y*v.y;
      acc += wr4[c4].z*v.z; acc += wr4[c4].w*v.w;
    }
    float xn = (acc - mu) * rsv;
    float yv = xn*ga + be;
    yv = yv > 0.f ? yv : LEAK*yv;
    m = fmaxf(m, yv);
  }
  fout[(size_t)(b*Nq + q0 + ql)*O + o] = m;
}

extern "C" void kernel_launch(void* const* d_in, const int* in_sizes, int n_in,
                              void* d_out, int out_size, void* d_ws, size_t ws_size,
                              hipStream_t stream) {
  const float* x    = (const float*)d_in[0];
  const float* w_in = (const float*)d_in[3];
  const float* b_in = (const float*)d_in[4];
  const float* w1 = (const float*)d_in[5];
  const float* g1 = (const float*)d_in[6];
  const float* be1= (const float*)d_in[7];
  const float* w2 = (const float*)d_in[8];
  const float* g2 = (const float*)d_in[9];
  const float* be2= (const float*)d_in[10];
  const float* w3 = (const float*)d_in[11];
  const float* g3 = (const float*)d_in[12];
  const float* be3= (const float*)d_in[13];
  const float* w4 = (const float*)d_in[14];
  const float* g4 = (const float*)d_in[15];
  const float* be4= (const float*)d_in[16];
  float* out = (float*)d_out;
  (void)in_sizes; (void)n_in; (void)out_size; (void)ws_size;

  char* ws = (char*)d_ws;
  size_t off = 0;
  auto alloc = [&](size_t count) {
    void* p = ws + off;
    off += (count * 4 + 255) & ~(size_t)255;
    return p;
  };
  float* f0    = (float*)alloc(16*2048*8);
  float* f1    = (float*)alloc(16*2048*32);
  float* f2    = (float*)alloc(16*512*64);
  float* f3    = (float*)alloc(16*512*64);
  float* fq1   = (float*)alloc(16*512*32);
  float* fq2   = (float*)alloc(16*128*64);
  float* cq1   = (float*)alloc(16*512*3);
  float* basep = (float*)alloc(16*2048*32);
  double2* pp  = (double2*)alloc(16*4*8*4);      // 512 double2
  int* idx1    = (int*)alloc(16*2048*16);
  int* idx2    = (int*)alloc(16*512*16);
  int* idx3    = (int*)alloc(16*512*16);
  int* idx4    = (int*)alloc(16*128*16);
  int* fidx1   = (int*)alloc(16*512);
  int* fidx2   = (int*)alloc(16*128);
  u64* part    = (u64*)alloc(2 * 16*2048*2*16);  // 8 MB (1M u64)
  u64* partB   = part + 16*512*4*16;             // second half for knn3

  float* cq2 = out;              // (16,128,3)
  float* f4  = out + 16*128*3;   // (16,128,128)

  // ---- layer 1 (+ fps1 overlapped) ----
  fusedA_kernel<<<400, 256, 0, stream>>>(x, w_in, b_in, f0, part, fidx1);
  fusedC1_kernel<<<4224, 256, 0, stream>>>(part, idx1, f0, w1, basep);
  stats_part_kernel<8,32><<<512, 256, 0, stream>>>(f0, 2048, idx1, 2048, basep, w1, pp);
  fin_kernel<8,32,8><<<4096, 256, 0, stream>>>(f0, 2048, idx1, 2048, basep, w1, pp, g1, be1, f1);
  gather_kernel<<<32, 256, 0, stream>>>(x, f1, 2048, 32, fidx1, 512, cq1, fq1);

  // ---- layer 2+3 knn + fps2 overlapped ----
  fusedB_kernel<<<272, 256, 0, stream>>>(cq1, x, part, partB, fidx2);
  fusedC2_kernel<<<2112, 256, 0, stream>>>(part, idx2, partB, idx3, fq1, w2, basep);
  stats_part_kernel<32,64><<<512, 256, 0, stream>>>(f1, 2048, idx2, 512, basep, w2, pp);
  fin_kernel<32,64,4><<<2048, 256, 0, stream>>>(f1, 2048, idx2, 512, basep, w2, pp, g2, be2, f2);

  // ---- layer 3 tail ----
  base3_kernel<<<2048, 256, 0, stream>>>(f2, w3, basep);
  stats_part_kernel<64,64><<<512, 256, 0, stream>>>(f2, 512, idx3, 512, basep, w3, pp);
  fin_kernel<64,64,4><<<2048, 256, 0, stream>>>(f2, 512, idx3, 512, basep, w3, pp, g3, be3, f3);
  gather_kernel<<<8, 256, 0, stream>>>(cq1, f3, 512, 64, fidx2, 128, cq2, fq2);

  // ---- layer 4 ----
  fusedD_kernel<<<1152, 256, 0, stream>>>(cq2, cq1, part, fq2, w4, basep);
  merge_kernel<<<8, 256, 0, stream>>>(part, 8, 16*128, idx4);
  stats_part_kernel<64,128><<<512, 256, 0, stream>>>(f3, 512, idx4, 128, basep, w4, pp);
  fin_kernel<64,128,2><<<1024, 256, 0, stream>>>(f3, 512, idx4, 128, basep, w4, pp, g4, be4, f4);
}